// Round 1
// baseline (13687.588 us; speedup 1.0000x reference)
//
#include <hip/hip_runtime.h>
#include <cmath>

// Problem constants (B, T, H) = (128, 1024, 512), fp32 throughout.
#define B_ 128
#define T_ 1024
#define H_ 512

// ---------------------------------------------------------------------------
// Phase 1: out[t,b,:] = X[b,t,:] @ Wx + bias   (fully parallel GEMM)
// M = B*T = 131072 rows (m = b*1024 + t), N = K = 512.
// 64x64 tile per block, 256 threads, 4x4 accumulators per thread, K-chunk 16.
// Writes directly into d_out at row (t*128 + b) -> phase 2 updates in place.
// ---------------------------------------------------------------------------
__global__ __launch_bounds__(256) void xw_gemm(const float* __restrict__ X,
                                               const float* __restrict__ Wx,
                                               const float* __restrict__ bias,
                                               float* __restrict__ out) {
  const int m0 = blockIdx.x * 64;
  const int n0 = blockIdx.y * 64;

  __shared__ float As[16][64];  // [k][m]
  __shared__ float Bs[16][64];  // [k][n]

  const int tid = threadIdx.x;
  const int ti = tid >> 4;  // 0..15 (m sub-tile)
  const int tj = tid & 15;  // 0..15 (n sub-tile)

  // staging assignments
  const int ra = tid >> 2;         // 0..63   (A row within tile)
  const int ca = (tid & 3) << 2;   // 0,4,8,12 (A k within chunk, float4)
  const int kb = tid >> 4;         // 0..15   (B k within chunk)
  const int nb = (tid & 15) << 2;  // 0..60   (B col within tile, float4)

  float acc[4][4] = {};

  for (int k0 = 0; k0 < H_; k0 += 16) {
    // stage A tile (64 m x 16 k), transposed into As[k][m]
    const float4 a4 =
        *reinterpret_cast<const float4*>(X + (size_t)(m0 + ra) * H_ + k0 + ca);
    As[ca + 0][ra] = a4.x;
    As[ca + 1][ra] = a4.y;
    As[ca + 2][ra] = a4.z;
    As[ca + 3][ra] = a4.w;
    // stage B tile (16 k x 64 n), direct
    *reinterpret_cast<float4*>(&Bs[kb][nb]) =
        *reinterpret_cast<const float4*>(Wx + (size_t)(k0 + kb) * H_ + n0 + nb);
    __syncthreads();

#pragma unroll
    for (int kk = 0; kk < 16; ++kk) {
      const float4 a = *reinterpret_cast<const float4*>(&As[kk][ti << 2]);
      const float4 b = *reinterpret_cast<const float4*>(&Bs[kk][tj << 2]);
      acc[0][0] = fmaf(a.x, b.x, acc[0][0]);
      acc[0][1] = fmaf(a.x, b.y, acc[0][1]);
      acc[0][2] = fmaf(a.x, b.z, acc[0][2]);
      acc[0][3] = fmaf(a.x, b.w, acc[0][3]);
      acc[1][0] = fmaf(a.y, b.x, acc[1][0]);
      acc[1][1] = fmaf(a.y, b.y, acc[1][1]);
      acc[1][2] = fmaf(a.y, b.z, acc[1][2]);
      acc[1][3] = fmaf(a.y, b.w, acc[1][3]);
      acc[2][0] = fmaf(a.z, b.x, acc[2][0]);
      acc[2][1] = fmaf(a.z, b.y, acc[2][1]);
      acc[2][2] = fmaf(a.z, b.z, acc[2][2]);
      acc[2][3] = fmaf(a.z, b.w, acc[2][3]);
      acc[3][0] = fmaf(a.w, b.x, acc[3][0]);
      acc[3][1] = fmaf(a.w, b.y, acc[3][1]);
      acc[3][2] = fmaf(a.w, b.z, acc[3][2]);
      acc[3][3] = fmaf(a.w, b.w, acc[3][3]);
    }
    __syncthreads();
  }

  const float4 bv =
      *reinterpret_cast<const float4*>(bias + n0 + (tj << 2));
#pragma unroll
  for (int ii = 0; ii < 4; ++ii) {
    const int m = m0 + (ti << 2) + ii;
    const int b = m >> 10;    // m / 1024
    const int t = m & 1023;   // m % 1024
    float4 v;
    v.x = acc[ii][0] + bv.x;
    v.y = acc[ii][1] + bv.y;
    v.z = acc[ii][2] + bv.z;
    v.w = acc[ii][3] + bv.w;
    *reinterpret_cast<float4*>(out + ((size_t)t * B_ + b) * H_ + n0 +
                               (tj << 2)) = v;
  }
}

// ---------------------------------------------------------------------------
// Phase 2: sequential recurrence, in place on d_out.
//   h_t[b,:] = tanh(out[t,b,:] + h_{t-1}[b,:] @ Wh);  out[t,b,:] = h_t[b,:]
// Batch rows are independent -> one WG per PAIR of batch rows (M_b=2 halves
// the per-step Wh L2 traffic vs one-row-per-WG; each Wh element loaded once,
// used for 2 fmacs). 64 WGs x 512 threads; h pair lives in LDS as float2
// (uniform-address ds_read_b64 broadcast, conflict-free).
// ---------------------------------------------------------------------------
__global__ __launch_bounds__(512) void rnn_recurrence(
    const float* __restrict__ state0, const float* __restrict__ Wh,
    float* __restrict__ out) {
  const int j = threadIdx.x;       // output column 0..511
  const int b0 = blockIdx.x * 2;   // batch rows owned by this WG
  const int b1 = b0 + 1;

  __shared__ float2 hh[H_];  // (h[b0][k], h[b1][k])

  hh[j] = make_float2(state0[(size_t)b0 * H_ + j], state0[(size_t)b1 * H_ + j]);
  __syncthreads();

  const float* __restrict__ wp = Wh + j;  // column j, stride H_ over k

  for (int t = 0; t < T_; ++t) {
    float* o0 = out + (size_t)t * (B_ * H_) + (size_t)b0 * H_ + j;
    float* o1 = o0 + H_;
    float acc0 = *o0;  // precomputed x@Wx + b
    float acc1 = *o1;

#pragma unroll 8
    for (int k = 0; k < H_; ++k) {
      const float2 h2 = hh[k];
      const float w = wp[(size_t)k * H_];
      acc0 = fmaf(h2.x, w, acc0);
      acc1 = fmaf(h2.y, w, acc1);
    }

    const float v0 = tanhf(acc0);
    const float v1 = tanhf(acc1);

    __syncthreads();  // all k-loop reads of hh done before overwrite
    hh[j] = make_float2(v0, v1);
    *o0 = v0;
    *o1 = v1;
    __syncthreads();  // new h visible before next step's reads
  }
}

extern "C" void kernel_launch(void* const* d_in, const int* in_sizes, int n_in,
                              void* d_out, int out_size, void* d_ws,
                              size_t ws_size, hipStream_t stream) {
  const float* X     = (const float*)d_in[0];  // [B, T, H]
  const float* state = (const float*)d_in[1];  // [1, B, H] (zeros)
  const float* Wx    = (const float*)d_in[2];  // [H, H]
  const float* Wh    = (const float*)d_in[3];  // [H, H]
  const float* bias  = (const float*)d_in[4];  // [H]
  float* out = (float*)d_out;                  // [T, B, H]

  // Phase 1: M/64 = 2048 tiles x N/64 = 8 tiles
  hipLaunchKernelGGL(xw_gemm, dim3(2048, 8), dim3(256), 0, stream, X, Wx, bias,
                     out);
  // Phase 2: 64 WGs (2 batch rows each), sequential over T inside the kernel
  hipLaunchKernelGGL(rnn_recurrence, dim3(64), dim3(512), 0, stream, state, Wh,
                     out);
}